// Round 6
// baseline (258.536 us; speedup 1.0000x reference)
//
#include <hip/hip_runtime.h>
#include <hip/hip_bf16.h>

// ---------------------------------------------------------------------------
// Fused pipeline: [x @ Wqkv + b] -> GQA sliding-window attn (W=256, zero-pad
// softmax semantics, no 1/sqrt(d)) -> [attn @ Wo + bo]
// B=2 S=4096 DIM=1024 H=16 KV=2 D=64  -> rows = 8192
// ---------------------------------------------------------------------------

typedef __attribute__((ext_vector_type(4))) float f32x4;
typedef __attribute__((ext_vector_type(8))) short s16x8;
typedef __attribute__((ext_vector_type(4))) short s16x4;

#define SEQ    4096
#define NROWS  8192
#define QKV_N  1280   // 1024 q | 128 k | 128 v

__device__ __forceinline__ unsigned short f2bf(float f) {
  union { float f; unsigned int u; } v; v.f = f;
  return (unsigned short)((v.u + 0x7FFFu + ((v.u >> 16) & 1u)) >> 16); // RNE
}

__device__ __forceinline__ unsigned int pk2(float lo, float hi) {
  __hip_bfloat162 h = __float22bfloat162_rn(make_float2(lo, hi));
  union { __hip_bfloat162 h; unsigned int u; } c; c.h = h;
  return c.u;
}

__device__ __forceinline__ void glds16(void* lds, const void* g) {
  void* gg = const_cast<void*>(g);
  __builtin_amdgcn_global_load_lds((__attribute__((address_space(1))) void*)gg,
                                   (__attribute__((address_space(3))) void*)lds,
                                   16, 0, 0);
}

__device__ __forceinline__ f32x4 mfma16(s16x8 a, s16x8 b, f32x4 c) {
  return __builtin_amdgcn_mfma_f32_16x16x32_bf16(a, b, c, 0, 0, 0);
}

// ---------------------------------------------------------------------------
// prep kernels
// ---------------------------------------------------------------------------
__global__ void convert_x(const float* __restrict__ x,
                          unsigned short* __restrict__ xb, int n) {
  int idx = (blockIdx.x * 256 + threadIdx.x) * 4;
  if (idx >= n) return;
  f32x4 v = *(const f32x4*)(x + idx);
  s16x4 o;
  o[0] = (short)f2bf(v[0]); o[1] = (short)f2bf(v[1]);
  o[2] = (short)f2bf(v[2]); o[3] = (short)f2bf(v[3]);
  *(s16x4*)(xb + idx) = o;
}

__global__ void transpose_qkv(const float* __restrict__ Wq,
                              const float* __restrict__ Wk,
                              const float* __restrict__ Wv,
                              unsigned short* __restrict__ Wt) {
  __shared__ float tile[32][33];
  int k0 = blockIdx.x * 32, n0 = blockIdx.y * 32;
  const float* src; int ld, cn0;
  if (n0 < 1024)      { src = Wq; ld = 1024; cn0 = n0; }
  else if (n0 < 1152) { src = Wk; ld = 128;  cn0 = n0 - 1024; }
  else                { src = Wv; ld = 128;  cn0 = n0 - 1152; }
  int tx = threadIdx.x, ty = threadIdx.y;
  #pragma unroll
  for (int r = 0; r < 32; r += 8)
    tile[ty + r][tx] = src[(k0 + ty + r) * ld + cn0 + tx];
  __syncthreads();
  #pragma unroll
  for (int r = 0; r < 32; r += 8)
    Wt[(n0 + ty + r) * 1024 + k0 + tx] = f2bf(tile[tx][ty + r]);
}

__global__ void transpose_wo(const float* __restrict__ W,
                             unsigned short* __restrict__ Wt) {
  __shared__ float tile[32][33];
  int k0 = blockIdx.x * 32, n0 = blockIdx.y * 32;
  int tx = threadIdx.x, ty = threadIdx.y;
  #pragma unroll
  for (int r = 0; r < 32; r += 8)
    tile[ty + r][tx] = W[(k0 + ty + r) * 1024 + n0 + tx];
  __syncthreads();
  #pragma unroll
  for (int r = 0; r < 32; r += 8)
    Wt[(n0 + ty + r) * 1024 + k0 + tx] = f2bf(tile[tx][ty + r]);
}

// ---------------------------------------------------------------------------
// m97-style 128x128 bf16 GEMM, B^T input, fused bias epilogue
// ---------------------------------------------------------------------------
template<bool BIAS3, bool OUT_F32>
__global__ __launch_bounds__(256)
void gemm_bt(const unsigned short* __restrict__ A,
             const unsigned short* __restrict__ Bt,
             void* __restrict__ Cv,
             const float* __restrict__ b0,
             const float* __restrict__ b1,
             const float* __restrict__ b2,
             int M, int N, int K) {
  __shared__ unsigned short la[128 * 32];
  __shared__ unsigned short lb[128 * 32];
  const int tid = threadIdx.x;
  const int lane = tid & 63;
  const int wv = tid >> 6;
  const int wr = wv >> 1, wc = wv & 1;
  const int l15 = lane & 15, lch = lane >> 4;
  const int row0 = blockIdx.x * 128;
  const int col0 = blockIdx.y * 128;

  f32x4 acc[4][4] = {};

  const int cc0 = tid, cc1 = 256 + tid;
  const unsigned short* a0 = A + (row0 + (cc0 >> 2)) * K + (cc0 & 3) * 8;
  const unsigned short* a1 = A + (row0 + (cc1 >> 2)) * K + (cc1 & 3) * 8;
  const unsigned short* bp0 = Bt + (col0 + (cc0 >> 2)) * K + (cc0 & 3) * 8;
  const unsigned short* bp1 = Bt + (col0 + (cc1 >> 2)) * K + (cc1 & 3) * 8;
  unsigned short* la0 = &la[cc0 * 8];
  unsigned short* la1 = &la[cc1 * 8];
  unsigned short* lb0 = &lb[cc0 * 8];
  unsigned short* lb1 = &lb[cc1 * 8];

  for (int k0 = 0; k0 < K; k0 += 32) {
    __syncthreads();
    glds16(la0, a0 + k0);
    glds16(la1, a1 + k0);
    glds16(lb0, bp0 + k0);
    glds16(lb1, bp1 + k0);
    asm volatile("s_waitcnt vmcnt(0)" ::: "memory");
    __syncthreads();

    s16x8 af[4], bfr[4];
    #pragma unroll
    for (int mi = 0; mi < 4; ++mi)
      af[mi] = *(const s16x8*)&la[(wr * 64 + mi * 16 + l15) * 32 + lch * 8];
    #pragma unroll
    for (int ni = 0; ni < 4; ++ni)
      bfr[ni] = *(const s16x8*)&lb[(wc * 64 + ni * 16 + l15) * 32 + lch * 8];
    #pragma unroll
    for (int mi = 0; mi < 4; ++mi)
      #pragma unroll
      for (int ni = 0; ni < 4; ++ni)
        acc[mi][ni] = mfma16(af[mi], bfr[ni], acc[mi][ni]);
  }

  #pragma unroll
  for (int mi = 0; mi < 4; ++mi) {
    #pragma unroll
    for (int ni = 0; ni < 4; ++ni) {
      int c = col0 + wc * 64 + ni * 16 + l15;
      float bias;
      if constexpr (BIAS3)
        bias = (c < 1024) ? b0[c] : (c < 1152) ? b1[c - 1024] : b2[c - 1152];
      else
        bias = b0[c];
      #pragma unroll
      for (int j = 0; j < 4; ++j) {
        int r = row0 + wr * 64 + mi * 16 + lch * 4 + j;
        float v = acc[mi][ni][j] + bias;
        if constexpr (OUT_F32) ((float*)Cv)[(long)r * N + c] = v;
        else ((unsigned short*)Cv)[(long)r * N + c] = f2bf(v);
      }
    }
  }
}

// ---------------------------------------------------------------------------
// GQA sliding-window attention, v3 (v2 + spill fix + coalesced O store).
// block = (qt, kvh, b): 512 threads = 8 waves, wave w = head kvh*8+w.
// K/V staged once per kv-group. K via global_load_lds with pre-swizzled
// source. V transposed [d][sigma(u)] so PV A-frags are each lane's own QK^T
// output (swapped-operand trick) -- P never leaves registers.
// v3 changes: __launch_bounds__(512) (the ",2" capped VGPRs at 128 and
// spilled sc[20] -> 310 MB of scratch traffic); O bounced through LDS so
// global stores are full 128B lines instead of 2B scalars.
// ---------------------------------------------------------------------------
#define SPAN 320
#define VSTR 332   // 166 dwords == 6 mod 32 -> ~2-way banks; 8B-aligned rows

__global__ __launch_bounds__(512)
void attn_win(const unsigned short* __restrict__ qkv,
              unsigned short* __restrict__ aout) {
  __shared__ unsigned short Kl[SPAN * 64];   // row-major, XOR-swizzled
  __shared__ unsigned short Vt[64 * VSTR];   // [d][sigma(u)]
  __shared__ unsigned short OB[8 * 16 * 68]; // per-wave O bounce tiles

  const int tid = threadIdx.x;
  const int lane = tid & 63;
  const int w = tid >> 6;
  const int l15 = lane & 15, lch = lane >> 4;
  const int qt = blockIdx.x, kvh = blockIdx.y, b = blockIdx.z;
  const int h = kvh * 8 + w;
  const int qbase = qt * 64;
  const int kstart = qbase - 128;
  const int rowbase = b * SEQ;

  // ---- stage: V global loads (issued first, 5x16B per thread)
  s16x8 vv[5];
  #pragma unroll
  for (int i = 0; i < 5; ++i) {
    int cc = i * 512 + tid;
    int u = cc >> 3;
    int c8 = cc & 7;
    int key = kstart + u;
    key = key < 0 ? 0 : (key > SEQ - 1 ? SEQ - 1 : key);
    vv[i] = *(const s16x8*)(qkv + (long)(rowbase + key) * QKV_N + 1152 + kvh * 64 + c8 * 8);
  }
  // ---- K via global_load_lds, source pre-swizzled (dest stays linear)
  #pragma unroll
  for (int i = 0; i < 5; ++i) {
    int cc = i * 512 + tid;
    int u = cc >> 3;
    int c16s = (cc & 7) ^ (u & 7);
    int key = kstart + u;
    key = key < 0 ? 0 : (key > SEQ - 1 ? SEQ - 1 : key);
    glds16((char*)Kl + cc * 16,
           qkv + (long)(rowbase + key) * QKV_N + 1024 + kvh * 64 + c16s * 8);
  }
  // ---- V transposed writes with sigma-permuted column
  // sigma: u = (c<<5)|(s<<4)|(g<<2)|m  ->  col = (c<<5)|(g<<3)|(s<<2)|m
  #pragma unroll
  for (int i = 0; i < 5; ++i) {
    int cc = i * 512 + tid;
    int u = cc >> 3;
    int c8 = cc & 7;
    int su = (u & ~31) | (((u >> 2) & 3) << 3) | (((u >> 4) & 1) << 2) | (u & 3);
    #pragma unroll
    for (int j = 0; j < 8; ++j)
      Vt[(c8 * 8 + j) * VSTR + su] = (unsigned short)vv[i][j];
  }
  asm volatile("s_waitcnt vmcnt(0)" ::: "memory");
  __syncthreads();

  for (int mt = 0; mt < 4; ++mt) {
    // Q B-frag: col(q) = l15, k-chunk = lch*8 (+32 for second mfma)
    const unsigned short* qp =
        qkv + (long)(rowbase + qbase + mt * 16 + l15) * QKV_N + h * 64 + lch * 8;
    s16x8 qf0 = *(const s16x8*)qp;
    s16x8 qf1 = *(const s16x8*)(qp + 32);

    // swapped QK^T: D[col=q(l15)][row=key(lch*4+j)]
    f32x4 sc[20];
    #pragma unroll
    for (int kt = 0; kt < 20; ++kt) {
      int key = kt * 16 + l15;
      int swz = (key & 7) << 4;
      const char* kb = (const char*)Kl + key * 128;
      s16x8 k0 = *(const s16x8*)(kb + ((lch * 16) ^ swz));
      s16x8 k1 = *(const s16x8*)(kb + ((64 + lch * 16) ^ swz));
      f32x4 a = {0.f, 0.f, 0.f, 0.f};
      a = mfma16(k0, qf0, a);
      a = mfma16(k1, qf1, a);
      sc[kt] = a;
    }

    // mask: lane's query q = l15 (tq), keys u = kt*16 + lch*4 + j
    int tq = mt * 16 + l15;
    float mx = -3.0e38f;
    #pragma unroll
    for (int kt = 0; kt < 20; ++kt)
      #pragma unroll
      for (int j = 0; j < 4; ++j) {
        int u = kt * 16 + lch * 4 + j;
        int kpos = kstart + u;
        bool win = (u >= tq) && (u < tq + 256);
        bool inr = (kpos >= 0) && (kpos < SEQ);
        float v = win ? (inr ? sc[kt][j] : 0.0f) : -3.0e38f;
        sc[kt][j] = v;
        mx = fmaxf(mx, v);
      }
    mx = fmaxf(mx, __shfl_xor(mx, 16));
    mx = fmaxf(mx, __shfl_xor(mx, 32));
    float sm = 0.f;
    #pragma unroll
    for (int kt = 0; kt < 20; ++kt)
      #pragma unroll
      for (int j = 0; j < 4; ++j) {
        float p = __expf(sc[kt][j] - mx);
        sc[kt][j] = p;
        sm += p;
      }
    sm += __shfl_xor(sm, 16);
    sm += __shfl_xor(sm, 32);
    float inv = 1.0f / sm;
    #pragma unroll
    for (int kt = 0; kt < 20; ++kt)
      #pragma unroll
      for (int j = 0; j < 4; ++j) {
        int kpos = kstart + kt * 16 + lch * 4 + j;
        bool inr = (kpos >= 0) && (kpos < SEQ);
        sc[kt][j] = inr ? sc[kt][j] * inv : 0.0f;
      }

    // PV: A-frag = own-lane packed P (sigma-matched), B = Vt rows
    f32x4 oa[4] = {};
    #pragma unroll
    for (int c = 0; c < 10; ++c) {
      union { unsigned int wd[4]; s16x8 v; } af;
      af.wd[0] = pk2(sc[2 * c][0], sc[2 * c][1]);
      af.wd[1] = pk2(sc[2 * c][2], sc[2 * c][3]);
      af.wd[2] = pk2(sc[2 * c + 1][0], sc[2 * c + 1][1]);
      af.wd[3] = pk2(sc[2 * c + 1][2], sc[2 * c + 1][3]);
      #pragma unroll
      for (int nt = 0; nt < 4; ++nt) {
        const unsigned short* vp = &Vt[(nt * 16 + l15) * VSTR + c * 32 + lch * 8];
        union { unsigned long long q[2]; s16x8 v; } bf_;
        bf_.q[0] = *(const unsigned long long*)vp;
        bf_.q[1] = *(const unsigned long long*)(vp + 4);
        oa[nt] = mfma16(af.v, bf_.v, oa[nt]);
      }
    }

    // O store: bounce through per-wave LDS tile, then 16B/lane coalesced.
    // Wave-local only -> no barrier (same-wave LDS ordering via lgkmcnt).
    unsigned short* ob = OB + w * 16 * 68;
    #pragma unroll
    for (int nt = 0; nt < 4; ++nt)
      #pragma unroll
      for (int j = 0; j < 4; ++j)
        ob[(lch * 4 + j) * 68 + nt * 16 + l15] = f2bf(oa[nt][j]);
    int orow = lane >> 3, ochk = lane & 7;
    #pragma unroll
    for (int half = 0; half < 2; ++half) {
      s16x8 ov = *(const s16x8*)&ob[(half * 8 + orow) * 68 + ochk * 8];
      long r = rowbase + qbase + mt * 16 + half * 8 + orow;
      *(s16x8*)(aout + r * 1024 + h * 64 + ochk * 8) = ov;
    }
  }
}

// ---------------------------------------------------------------------------
extern "C" void kernel_launch(void* const* d_in, const int* in_sizes, int n_in,
                              void* d_out, int out_size, void* d_ws, size_t ws_size,
                              hipStream_t stream) {
  const float* x  = (const float*)d_in[0];
  const float* Wq = (const float*)d_in[1];
  const float* bq = (const float*)d_in[2];
  const float* Wk = (const float*)d_in[3];
  const float* bk = (const float*)d_in[4];
  const float* Wv = (const float*)d_in[5];
  const float* bv = (const float*)d_in[6];
  const float* Wo = (const float*)d_in[7];
  const float* bo = (const float*)d_in[8];
  float* out = (float*)d_out;

  // workspace layout (bytes): total ~42.5 MB; attno aliases dead xb
  char* ws = (char*)d_ws;
  unsigned short* xb    = (unsigned short*)(ws);
  unsigned short* attno = (unsigned short*)(ws);
  unsigned short* wqkvt = (unsigned short*)(ws + 16777216);
  unsigned short* wot   = (unsigned short*)(ws + 19398656);
  unsigned short* qkv   = (unsigned short*)(ws + 21495808);

  convert_x<<<8192, 256, 0, stream>>>(x, xb, NROWS * 1024);
  transpose_qkv<<<dim3(32, 40), dim3(32, 8), 0, stream>>>(Wq, Wk, Wv, wqkvt);
  transpose_wo<<<dim3(32, 32), dim3(32, 8), 0, stream>>>(Wo, wot);

  gemm_bt<true, false><<<dim3(NROWS / 128, QKV_N / 128), 256, 0, stream>>>(
      xb, wqkvt, (void*)qkv, bq, bk, bv, NROWS, QKV_N, 1024);

  attn_win<<<dim3(64, 2, 2), 512, 0, stream>>>(qkv, attno);

  gemm_bt<false, true><<<dim3(NROWS / 128, 1024 / 128), 256, 0, stream>>>(
      attno, wot, (void*)out, bo, nullptr, nullptr, NROWS, 1024, 1024);
}

// Round 8
// 258.026 us; speedup vs baseline: 1.0020x; 1.0020x over previous
//
#include <hip/hip_runtime.h>
#include <hip/hip_bf16.h>

// ---------------------------------------------------------------------------
// Fused pipeline: [x @ Wqkv + b] -> GQA sliding-window attn (W=256, zero-pad
// softmax semantics, no 1/sqrt(d)) -> [attn @ Wo + bo]
// B=2 S=4096 DIM=1024 H=16 KV=2 D=64  -> rows = 8192
// ---------------------------------------------------------------------------

typedef __attribute__((ext_vector_type(4))) float f32x4;
typedef __attribute__((ext_vector_type(8))) short s16x8;
typedef __attribute__((ext_vector_type(4))) short s16x4;

#define SEQ    4096
#define NROWS  8192
#define QKV_N  1280   // 1024 q | 128 k | 128 v

__device__ __forceinline__ unsigned short f2bf(float f) {
  union { float f; unsigned int u; } v; v.f = f;
  return (unsigned short)((v.u + 0x7FFFu + ((v.u >> 16) & 1u)) >> 16); // RNE
}

__device__ __forceinline__ unsigned int pk2(float lo, float hi) {
  __hip_bfloat162 h = __float22bfloat162_rn(make_float2(lo, hi));
  union { __hip_bfloat162 h; unsigned int u; } c; c.h = h;
  return c.u;
}

__device__ __forceinline__ void glds16(void* lds, const void* g) {
  void* gg = const_cast<void*>(g);
  __builtin_amdgcn_global_load_lds((__attribute__((address_space(1))) void*)gg,
                                   (__attribute__((address_space(3))) void*)lds,
                                   16, 0, 0);
}

__device__ __forceinline__ f32x4 mfma16(s16x8 a, s16x8 b, f32x4 c) {
  return __builtin_amdgcn_mfma_f32_16x16x32_bf16(a, b, c, 0, 0, 0);
}

// ---------------------------------------------------------------------------
// prep kernels
// ---------------------------------------------------------------------------
__global__ void convert_x(const float* __restrict__ x,
                          unsigned short* __restrict__ xb, int n) {
  int idx = (blockIdx.x * 256 + threadIdx.x) * 4;
  if (idx >= n) return;
  f32x4 v = *(const f32x4*)(x + idx);
  s16x4 o;
  o[0] = (short)f2bf(v[0]); o[1] = (short)f2bf(v[1]);
  o[2] = (short)f2bf(v[2]); o[3] = (short)f2bf(v[3]);
  *(s16x4*)(xb + idx) = o;
}

__global__ void transpose_qkv(const float* __restrict__ Wq,
                              const float* __restrict__ Wk,
                              const float* __restrict__ Wv,
                              unsigned short* __restrict__ Wt) {
  __shared__ float tile[32][33];
  int k0 = blockIdx.x * 32, n0 = blockIdx.y * 32;
  const float* src; int ld, cn0;
  if (n0 < 1024)      { src = Wq; ld = 1024; cn0 = n0; }
  else if (n0 < 1152) { src = Wk; ld = 128;  cn0 = n0 - 1024; }
  else                { src = Wv; ld = 128;  cn0 = n0 - 1152; }
  int tx = threadIdx.x, ty = threadIdx.y;
  #pragma unroll
  for (int r = 0; r < 32; r += 8)
    tile[ty + r][tx] = src[(k0 + ty + r) * ld + cn0 + tx];
  __syncthreads();
  #pragma unroll
  for (int r = 0; r < 32; r += 8)
    Wt[(n0 + ty + r) * 1024 + k0 + tx] = f2bf(tile[tx][ty + r]);
}

__global__ void transpose_wo(const float* __restrict__ W,
                             unsigned short* __restrict__ Wt) {
  __shared__ float tile[32][33];
  int k0 = blockIdx.x * 32, n0 = blockIdx.y * 32;
  int tx = threadIdx.x, ty = threadIdx.y;
  #pragma unroll
  for (int r = 0; r < 32; r += 8)
    tile[ty + r][tx] = W[(k0 + ty + r) * 1024 + n0 + tx];
  __syncthreads();
  #pragma unroll
  for (int r = 0; r < 32; r += 8)
    Wt[(n0 + ty + r) * 1024 + k0 + tx] = f2bf(tile[tx][ty + r]);
}

// ---------------------------------------------------------------------------
// m97-style 128x128 bf16 GEMM, B^T input, fused bias epilogue
// ---------------------------------------------------------------------------
template<bool BIAS3, bool OUT_F32>
__global__ __launch_bounds__(256)
void gemm_bt(const unsigned short* __restrict__ A,
             const unsigned short* __restrict__ Bt,
             void* __restrict__ Cv,
             const float* __restrict__ b0,
             const float* __restrict__ b1,
             const float* __restrict__ b2,
             int M, int N, int K) {
  __shared__ unsigned short la[128 * 32];
  __shared__ unsigned short lb[128 * 32];
  const int tid = threadIdx.x;
  const int lane = tid & 63;
  const int wv = tid >> 6;
  const int wr = wv >> 1, wc = wv & 1;
  const int l15 = lane & 15, lch = lane >> 4;
  const int row0 = blockIdx.x * 128;
  const int col0 = blockIdx.y * 128;

  f32x4 acc[4][4] = {};

  const int cc0 = tid, cc1 = 256 + tid;
  const unsigned short* a0 = A + (row0 + (cc0 >> 2)) * K + (cc0 & 3) * 8;
  const unsigned short* a1 = A + (row0 + (cc1 >> 2)) * K + (cc1 & 3) * 8;
  const unsigned short* bp0 = Bt + (col0 + (cc0 >> 2)) * K + (cc0 & 3) * 8;
  const unsigned short* bp1 = Bt + (col0 + (cc1 >> 2)) * K + (cc1 & 3) * 8;
  unsigned short* la0 = &la[cc0 * 8];
  unsigned short* la1 = &la[cc1 * 8];
  unsigned short* lb0 = &lb[cc0 * 8];
  unsigned short* lb1 = &lb[cc1 * 8];

  for (int k0 = 0; k0 < K; k0 += 32) {
    __syncthreads();
    glds16(la0, a0 + k0);
    glds16(la1, a1 + k0);
    glds16(lb0, bp0 + k0);
    glds16(lb1, bp1 + k0);
    asm volatile("s_waitcnt vmcnt(0)" ::: "memory");
    __syncthreads();

    s16x8 af[4], bfr[4];
    #pragma unroll
    for (int mi = 0; mi < 4; ++mi)
      af[mi] = *(const s16x8*)&la[(wr * 64 + mi * 16 + l15) * 32 + lch * 8];
    #pragma unroll
    for (int ni = 0; ni < 4; ++ni)
      bfr[ni] = *(const s16x8*)&lb[(wc * 64 + ni * 16 + l15) * 32 + lch * 8];
    #pragma unroll
    for (int mi = 0; mi < 4; ++mi)
      #pragma unroll
      for (int ni = 0; ni < 4; ++ni)
        acc[mi][ni] = mfma16(af[mi], bfr[ni], acc[mi][ni]);
  }

  #pragma unroll
  for (int mi = 0; mi < 4; ++mi) {
    #pragma unroll
    for (int ni = 0; ni < 4; ++ni) {
      int c = col0 + wc * 64 + ni * 16 + l15;
      float bias;
      if constexpr (BIAS3)
        bias = (c < 1024) ? b0[c] : (c < 1152) ? b1[c - 1024] : b2[c - 1152];
      else
        bias = b0[c];
      #pragma unroll
      for (int j = 0; j < 4; ++j) {
        int r = row0 + wr * 64 + mi * 16 + lch * 4 + j;
        float v = acc[mi][ni][j] + bias;
        if constexpr (OUT_F32) ((float*)Cv)[(long)r * N + c] = v;
        else ((unsigned short*)Cv)[(long)r * N + c] = f2bf(v);
      }
    }
  }
}

// ---------------------------------------------------------------------------
// GQA sliding-window attention, v4 (v3 + amdgpu_waves_per_eu(2,2)).
// block = (qt, kvh, b): 512 threads = 8 waves, wave w = head kvh*8+w.
// Occupancy is LDS-capped at 1 block/CU = 2 waves/EU; telling the allocator
// so (waves_per_eu max=2) lifts its default 4-waves/EU VGPR budget (128,
// which spilled sc[20] -> ~300 MB scratch traffic in v2/v3) to 256.
// K via global_load_lds with pre-swizzled source. V transposed [d][sigma(u)]
// so PV A-frags are each lane's own QK^T output -- P never leaves registers.
// Zero-pad semantics: clamped-address staging; in-window OOB keys get raw
// score 0 (counted in denominator), P forced 0 there (V garbage nullified).
// ---------------------------------------------------------------------------
#define SPAN 320
#define VSTR 332   // 166 dwords == 6 mod 32 -> ~2-way banks; 8B-aligned rows

__global__ __launch_bounds__(512)
__attribute__((amdgpu_waves_per_eu(2, 2)))
void attn_win(const unsigned short* __restrict__ qkv,
              unsigned short* __restrict__ aout) {
  __shared__ unsigned short Kl[SPAN * 64];   // row-major, XOR-swizzled
  __shared__ unsigned short Vt[64 * VSTR];   // [d][sigma(u)]
  __shared__ unsigned short OB[8 * 16 * 68]; // per-wave O bounce tiles

  const int tid = threadIdx.x;
  const int lane = tid & 63;
  const int w = tid >> 6;
  const int l15 = lane & 15, lch = lane >> 4;
  const int qt = blockIdx.x, kvh = blockIdx.y, b = blockIdx.z;
  const int h = kvh * 8 + w;
  const int qbase = qt * 64;
  const int kstart = qbase - 128;
  const int rowbase = b * SEQ;

  // ---- stage: V global loads (issued first, 5x16B per thread)
  s16x8 vv[5];
  #pragma unroll
  for (int i = 0; i < 5; ++i) {
    int cc = i * 512 + tid;
    int u = cc >> 3;
    int c8 = cc & 7;
    int key = kstart + u;
    key = key < 0 ? 0 : (key > SEQ - 1 ? SEQ - 1 : key);
    vv[i] = *(const s16x8*)(qkv + (long)(rowbase + key) * QKV_N + 1152 + kvh * 64 + c8 * 8);
  }
  // ---- K via global_load_lds, source pre-swizzled (dest stays linear)
  #pragma unroll
  for (int i = 0; i < 5; ++i) {
    int cc = i * 512 + tid;
    int u = cc >> 3;
    int c16s = (cc & 7) ^ (u & 7);
    int key = kstart + u;
    key = key < 0 ? 0 : (key > SEQ - 1 ? SEQ - 1 : key);
    glds16((char*)Kl + cc * 16,
           qkv + (long)(rowbase + key) * QKV_N + 1024 + kvh * 64 + c16s * 8);
  }
  // ---- V transposed writes with sigma-permuted column
  // sigma: u = (c<<5)|(s<<4)|(g<<2)|m  ->  col = (c<<5)|(g<<3)|(s<<2)|m
  #pragma unroll
  for (int i = 0; i < 5; ++i) {
    int cc = i * 512 + tid;
    int u = cc >> 3;
    int c8 = cc & 7;
    int su = (u & ~31) | (((u >> 2) & 3) << 3) | (((u >> 4) & 1) << 2) | (u & 3);
    #pragma unroll
    for (int j = 0; j < 8; ++j)
      Vt[(c8 * 8 + j) * VSTR + su] = (unsigned short)vv[i][j];
  }
  asm volatile("s_waitcnt vmcnt(0)" ::: "memory");
  __syncthreads();

  for (int mt = 0; mt < 4; ++mt) {
    // Q B-frag: col(q) = l15, k-chunk = lch*8 (+32 for second mfma)
    const unsigned short* qp =
        qkv + (long)(rowbase + qbase + mt * 16 + l15) * QKV_N + h * 64 + lch * 8;
    s16x8 qf0 = *(const s16x8*)qp;
    s16x8 qf1 = *(const s16x8*)(qp + 32);

    // swapped QK^T: D[col=q(l15)][row=key(lch*4+j)]
    f32x4 sc[20];
    #pragma unroll
    for (int kt = 0; kt < 20; ++kt) {
      int key = kt * 16 + l15;
      int swz = (key & 7) << 4;
      const char* kb = (const char*)Kl + key * 128;
      s16x8 k0 = *(const s16x8*)(kb + ((lch * 16) ^ swz));
      s16x8 k1 = *(const s16x8*)(kb + ((64 + lch * 16) ^ swz));
      f32x4 a = {0.f, 0.f, 0.f, 0.f};
      a = mfma16(k0, qf0, a);
      a = mfma16(k1, qf1, a);
      sc[kt] = a;
    }

    // mask: lane's query q = l15 (tq), keys u = kt*16 + lch*4 + j
    int tq = mt * 16 + l15;
    float mx = -3.0e38f;
    #pragma unroll
    for (int kt = 0; kt < 20; ++kt)
      #pragma unroll
      for (int j = 0; j < 4; ++j) {
        int u = kt * 16 + lch * 4 + j;
        int kpos = kstart + u;
        bool win = (u >= tq) && (u < tq + 256);
        bool inr = (kpos >= 0) && (kpos < SEQ);
        float v = win ? (inr ? sc[kt][j] : 0.0f) : -3.0e38f;
        sc[kt][j] = v;
        mx = fmaxf(mx, v);
      }
    mx = fmaxf(mx, __shfl_xor(mx, 16));
    mx = fmaxf(mx, __shfl_xor(mx, 32));
    float sm = 0.f;
    #pragma unroll
    for (int kt = 0; kt < 20; ++kt)
      #pragma unroll
      for (int j = 0; j < 4; ++j) {
        float p = __expf(sc[kt][j] - mx);
        sc[kt][j] = p;
        sm += p;
      }
    sm += __shfl_xor(sm, 16);
    sm += __shfl_xor(sm, 32);
    float inv = 1.0f / sm;
    #pragma unroll
    for (int kt = 0; kt < 20; ++kt)
      #pragma unroll
      for (int j = 0; j < 4; ++j) {
        int kpos = kstart + kt * 16 + lch * 4 + j;
        bool inr = (kpos >= 0) && (kpos < SEQ);
        sc[kt][j] = inr ? sc[kt][j] * inv : 0.0f;
      }

    // PV: A-frag = own-lane packed P (sigma-matched), B = Vt rows
    f32x4 oa[4] = {};
    #pragma unroll
    for (int c = 0; c < 10; ++c) {
      union { unsigned int wd[4]; s16x8 v; } af;
      af.wd[0] = pk2(sc[2 * c][0], sc[2 * c][1]);
      af.wd[1] = pk2(sc[2 * c][2], sc[2 * c][3]);
      af.wd[2] = pk2(sc[2 * c + 1][0], sc[2 * c + 1][1]);
      af.wd[3] = pk2(sc[2 * c + 1][2], sc[2 * c + 1][3]);
      #pragma unroll
      for (int nt = 0; nt < 4; ++nt) {
        const unsigned short* vp = &Vt[(nt * 16 + l15) * VSTR + c * 32 + lch * 8];
        union { unsigned long long q[2]; s16x8 v; } bf_;
        bf_.q[0] = *(const unsigned long long*)vp;
        bf_.q[1] = *(const unsigned long long*)(vp + 4);
        oa[nt] = mfma16(af.v, bf_.v, oa[nt]);
      }
    }

    // O store: bounce through per-wave LDS tile, then 16B/lane coalesced.
    // Wave-local only -> no barrier (same-wave LDS ordering via lgkmcnt).
    unsigned short* ob = OB + w * 16 * 68;
    #pragma unroll
    for (int nt = 0; nt < 4; ++nt)
      #pragma unroll
      for (int j = 0; j < 4; ++j)
        ob[(lch * 4 + j) * 68 + nt * 16 + l15] = f2bf(oa[nt][j]);
    int orow = lane >> 3, ochk = lane & 7;
    #pragma unroll
    for (int half = 0; half < 2; ++half) {
      s16x8 ov = *(const s16x8*)&ob[(half * 8 + orow) * 68 + ochk * 8];
      long r = rowbase + qbase + mt * 16 + half * 8 + orow;
      *(s16x8*)(aout + r * 1024 + h * 64 + ochk * 8) = ov;
    }
  }
}

// ---------------------------------------------------------------------------
extern "C" void kernel_launch(void* const* d_in, const int* in_sizes, int n_in,
                              void* d_out, int out_size, void* d_ws, size_t ws_size,
                              hipStream_t stream) {
  const float* x  = (const float*)d_in[0];
  const float* Wq = (const float*)d_in[1];
  const float* bq = (const float*)d_in[2];
  const float* Wk = (const float*)d_in[3];
  const float* bk = (const float*)d_in[4];
  const float* Wv = (const float*)d_in[5];
  const float* bv = (const float*)d_in[6];
  const float* Wo = (const float*)d_in[7];
  const float* bo = (const float*)d_in[8];
  float* out = (float*)d_out;

  // workspace layout (bytes): total ~42.5 MB; attno aliases dead xb
  char* ws = (char*)d_ws;
  unsigned short* xb    = (unsigned short*)(ws);
  unsigned short* attno = (unsigned short*)(ws);
  unsigned short* wqkvt = (unsigned short*)(ws + 16777216);
  unsigned short* wot   = (unsigned short*)(ws + 19398656);
  unsigned short* qkv   = (unsigned short*)(ws + 21495808);

  convert_x<<<8192, 256, 0, stream>>>(x, xb, NROWS * 1024);
  transpose_qkv<<<dim3(32, 40), dim3(32, 8), 0, stream>>>(Wq, Wk, Wv, wqkvt);
  transpose_wo<<<dim3(32, 32), dim3(32, 8), 0, stream>>>(Wo, wot);

  gemm_bt<true, false><<<dim3(NROWS / 128, QKV_N / 128), 256, 0, stream>>>(
      xb, wqkvt, (void*)qkv, bq, bk, bv, NROWS, QKV_N, 1024);

  attn_win<<<dim3(64, 2, 2), 512, 0, stream>>>(qkv, attno);

  gemm_bt<false, true><<<dim3(NROWS / 128, 1024 / 128), 256, 0, stream>>>(
      attno, wot, (void*)out, bo, nullptr, nullptr, NROWS, 1024, 1024);
}

// Round 10
// 235.470 us; speedup vs baseline: 1.0980x; 1.0958x over previous
//
#include <hip/hip_runtime.h>
#include <hip/hip_bf16.h>

// ---------------------------------------------------------------------------
// Fused pipeline: [x @ Wqkv + b] -> GQA sliding-window attn (W=256, zero-pad
// softmax semantics, no 1/sqrt(d)) -> [attn @ Wo + bo]
// B=2 S=4096 DIM=1024 H=16 KV=2 D=64  -> rows = 8192
// ---------------------------------------------------------------------------

typedef __attribute__((ext_vector_type(4))) float f32x4;
typedef __attribute__((ext_vector_type(8))) short s16x8;
typedef __attribute__((ext_vector_type(4))) short s16x4;

#define SEQ    4096
#define NROWS  8192
#define QKV_N  1280   // 1024 q | 128 k | 128 v

__device__ __forceinline__ unsigned short f2bf(float f) {
  union { float f; unsigned int u; } v; v.f = f;
  return (unsigned short)((v.u + 0x7FFFu + ((v.u >> 16) & 1u)) >> 16); // RNE
}

__device__ __forceinline__ unsigned int pk2(float lo, float hi) {
  __hip_bfloat162 h = __float22bfloat162_rn(make_float2(lo, hi));
  union { __hip_bfloat162 h; unsigned int u; } c; c.h = h;
  return c.u;
}

__device__ __forceinline__ void glds16(void* lds, const void* g) {
  void* gg = const_cast<void*>(g);
  __builtin_amdgcn_global_load_lds((__attribute__((address_space(1))) void*)gg,
                                   (__attribute__((address_space(3))) void*)lds,
                                   16, 0, 0);
}

__device__ __forceinline__ f32x4 mfma16(s16x8 a, s16x8 b, f32x4 c) {
  return __builtin_amdgcn_mfma_f32_16x16x32_bf16(a, b, c, 0, 0, 0);
}

// ---------------------------------------------------------------------------
// prep kernels
// ---------------------------------------------------------------------------
__global__ void convert_x(const float* __restrict__ x,
                          unsigned short* __restrict__ xb, int n) {
  int idx = (blockIdx.x * 256 + threadIdx.x) * 4;
  if (idx >= n) return;
  f32x4 v = *(const f32x4*)(x + idx);
  s16x4 o;
  o[0] = (short)f2bf(v[0]); o[1] = (short)f2bf(v[1]);
  o[2] = (short)f2bf(v[2]); o[3] = (short)f2bf(v[3]);
  *(s16x4*)(xb + idx) = o;
}

__global__ void transpose_qkv(const float* __restrict__ Wq,
                              const float* __restrict__ Wk,
                              const float* __restrict__ Wv,
                              unsigned short* __restrict__ Wt) {
  __shared__ float tile[32][33];
  int k0 = blockIdx.x * 32, n0 = blockIdx.y * 32;
  const float* src; int ld, cn0;
  if (n0 < 1024)      { src = Wq; ld = 1024; cn0 = n0; }
  else if (n0 < 1152) { src = Wk; ld = 128;  cn0 = n0 - 1024; }
  else                { src = Wv; ld = 128;  cn0 = n0 - 1152; }
  int tx = threadIdx.x, ty = threadIdx.y;
  #pragma unroll
  for (int r = 0; r < 32; r += 8)
    tile[ty + r][tx] = src[(k0 + ty + r) * ld + cn0 + tx];
  __syncthreads();
  #pragma unroll
  for (int r = 0; r < 32; r += 8)
    Wt[(n0 + ty + r) * 1024 + k0 + tx] = f2bf(tile[tx][ty + r]);
}

__global__ void transpose_wo(const float* __restrict__ W,
                             unsigned short* __restrict__ Wt) {
  __shared__ float tile[32][33];
  int k0 = blockIdx.x * 32, n0 = blockIdx.y * 32;
  int tx = threadIdx.x, ty = threadIdx.y;
  #pragma unroll
  for (int r = 0; r < 32; r += 8)
    tile[ty + r][tx] = W[(k0 + ty + r) * 1024 + n0 + tx];
  __syncthreads();
  #pragma unroll
  for (int r = 0; r < 32; r += 8)
    Wt[(n0 + ty + r) * 1024 + k0 + tx] = f2bf(tile[tx][ty + r]);
}

// ---------------------------------------------------------------------------
// m97-style 128x128 bf16 GEMM, B^T input, fused bias epilogue
// ---------------------------------------------------------------------------
template<bool BIAS3, bool OUT_F32>
__global__ __launch_bounds__(256)
void gemm_bt(const unsigned short* __restrict__ A,
             const unsigned short* __restrict__ Bt,
             void* __restrict__ Cv,
             const float* __restrict__ b0,
             const float* __restrict__ b1,
             const float* __restrict__ b2,
             int M, int N, int K) {
  __shared__ unsigned short la[128 * 32];
  __shared__ unsigned short lb[128 * 32];
  const int tid = threadIdx.x;
  const int lane = tid & 63;
  const int wv = tid >> 6;
  const int wr = wv >> 1, wc = wv & 1;
  const int l15 = lane & 15, lch = lane >> 4;
  const int row0 = blockIdx.x * 128;
  const int col0 = blockIdx.y * 128;

  f32x4 acc[4][4] = {};

  const int cc0 = tid, cc1 = 256 + tid;
  const unsigned short* a0 = A + (row0 + (cc0 >> 2)) * K + (cc0 & 3) * 8;
  const unsigned short* a1 = A + (row0 + (cc1 >> 2)) * K + (cc1 & 3) * 8;
  const unsigned short* bp0 = Bt + (col0 + (cc0 >> 2)) * K + (cc0 & 3) * 8;
  const unsigned short* bp1 = Bt + (col0 + (cc1 >> 2)) * K + (cc1 & 3) * 8;
  unsigned short* la0 = &la[cc0 * 8];
  unsigned short* la1 = &la[cc1 * 8];
  unsigned short* lb0 = &lb[cc0 * 8];
  unsigned short* lb1 = &lb[cc1 * 8];

  for (int k0 = 0; k0 < K; k0 += 32) {
    __syncthreads();
    glds16(la0, a0 + k0);
    glds16(la1, a1 + k0);
    glds16(lb0, bp0 + k0);
    glds16(lb1, bp1 + k0);
    asm volatile("s_waitcnt vmcnt(0)" ::: "memory");
    __syncthreads();

    s16x8 af[4], bfr[4];
    #pragma unroll
    for (int mi = 0; mi < 4; ++mi)
      af[mi] = *(const s16x8*)&la[(wr * 64 + mi * 16 + l15) * 32 + lch * 8];
    #pragma unroll
    for (int ni = 0; ni < 4; ++ni)
      bfr[ni] = *(const s16x8*)&lb[(wc * 64 + ni * 16 + l15) * 32 + lch * 8];
    #pragma unroll
    for (int mi = 0; mi < 4; ++mi)
      #pragma unroll
      for (int ni = 0; ni < 4; ++ni)
        acc[mi][ni] = mfma16(af[mi], bfr[ni], acc[mi][ni]);
  }

  #pragma unroll
  for (int mi = 0; mi < 4; ++mi) {
    #pragma unroll
    for (int ni = 0; ni < 4; ++ni) {
      int c = col0 + wc * 64 + ni * 16 + l15;
      float bias;
      if constexpr (BIAS3)
        bias = (c < 1024) ? b0[c] : (c < 1152) ? b1[c - 1024] : b2[c - 1152];
      else
        bias = b0[c];
      #pragma unroll
      for (int j = 0; j < 4; ++j) {
        int r = row0 + wr * 64 + mi * 16 + lch * 4 + j;
        float v = acc[mi][ni][j] + bias;
        if constexpr (OUT_F32) ((float*)Cv)[(long)r * N + c] = v;
        else ((unsigned short*)Cv)[(long)r * N + c] = f2bf(v);
      }
    }
  }
}

// ---------------------------------------------------------------------------
// GQA sliding-window attention, v6 = v5 + correct per-row normalization.
// v5's bug: lane's softmax sum belongs to query l15 (QK^T D: col=query), but
// PV D-output rows are query lch*4+j -- applying the lane's own inv at the
// O-store normalized the WRONG query's row (absmax 7551). v6 redistributes
// the reciprocal with __shfl(inv, lch*4+j) (sum for query q is complete in
// every lane with l15==q, so lanes 0-15 are valid broadcast sources).
// Spill-free structure kept from v5: no max-shift (scores |s|<~25 << 88),
// exp immediately per key-tile, pack unnormalized P to bf16 (40 VGPRs vs 80),
// denominator as scalar, normalize at O store. Peak live ~90 VGPRs.
// Zero-pad semantics: in-window OOB keys add exp(0)=1 to the denominator and
// contribute 0 to PV. Identical math to reference softmax.
// ---------------------------------------------------------------------------
#define SPAN 320
#define VSTR 332   // 166 dwords == 6 mod 32 -> ~2-way banks; 8B-aligned rows

__global__ __launch_bounds__(512)
void attn_win(const unsigned short* __restrict__ qkv,
              unsigned short* __restrict__ aout) {
  __shared__ unsigned short Kl[SPAN * 64];   // row-major, XOR-swizzled
  __shared__ unsigned short Vt[64 * VSTR];   // [d][sigma(u)]
  __shared__ unsigned short OB[8 * 16 * 68]; // per-wave O bounce tiles

  const int tid = threadIdx.x;
  const int lane = tid & 63;
  const int w = tid >> 6;
  const int l15 = lane & 15, lch = lane >> 4;
  const int qt = blockIdx.x, kvh = blockIdx.y, b = blockIdx.z;
  const int h = kvh * 8 + w;
  const int qbase = qt * 64;
  const int kstart = qbase - 128;
  const int rowbase = b * SEQ;

  // ---- stage: V global loads (issued first, 5x16B per thread)
  s16x8 vv[5];
  #pragma unroll
  for (int i = 0; i < 5; ++i) {
    int cc = i * 512 + tid;
    int u = cc >> 3;
    int c8 = cc & 7;
    int key = kstart + u;
    key = key < 0 ? 0 : (key > SEQ - 1 ? SEQ - 1 : key);
    vv[i] = *(const s16x8*)(qkv + (long)(rowbase + key) * QKV_N + 1152 + kvh * 64 + c8 * 8);
  }
  // ---- K via global_load_lds, source pre-swizzled (dest stays linear)
  #pragma unroll
  for (int i = 0; i < 5; ++i) {
    int cc = i * 512 + tid;
    int u = cc >> 3;
    int c16s = (cc & 7) ^ (u & 7);
    int key = kstart + u;
    key = key < 0 ? 0 : (key > SEQ - 1 ? SEQ - 1 : key);
    glds16((char*)Kl + cc * 16,
           qkv + (long)(rowbase + key) * QKV_N + 1024 + kvh * 64 + c16s * 8);
  }
  // ---- V transposed writes with sigma-permuted column
  // sigma: u = (c<<5)|(s<<4)|(g<<2)|m  ->  col = (c<<5)|(g<<3)|(s<<2)|m
  #pragma unroll
  for (int i = 0; i < 5; ++i) {
    int cc = i * 512 + tid;
    int u = cc >> 3;
    int c8 = cc & 7;
    int su = (u & ~31) | (((u >> 2) & 3) << 3) | (((u >> 4) & 1) << 2) | (u & 3);
    #pragma unroll
    for (int j = 0; j < 8; ++j)
      Vt[(c8 * 8 + j) * VSTR + su] = (unsigned short)vv[i][j];
  }
  asm volatile("s_waitcnt vmcnt(0)" ::: "memory");
  __syncthreads();

  for (int mt = 0; mt < 4; ++mt) {
    // Q B-frag: col(q) = l15, k-chunk = lch*8 (+32 for second mfma)
    const unsigned short* qp =
        qkv + (long)(rowbase + qbase + mt * 16 + l15) * QKV_N + h * 64 + lch * 8;
    s16x8 qf0 = *(const s16x8*)qp;
    s16x8 qf1 = *(const s16x8*)(qp + 32);

    // swapped QK^T + immediate exp + bf16 pack (no f32 score array kept).
    // Lane's softmax row = query l15 (tq); keys u = kt*16 + lch*4 + j.
    const int tq = mt * 16 + l15;
    float sum = 0.0f;
    unsigned int pw[40];
    #pragma unroll
    for (int kt = 0; kt < 20; ++kt) {
      int key = kt * 16 + l15;
      int swz = (key & 7) << 4;
      const char* kb = (const char*)Kl + key * 128;
      s16x8 k0 = *(const s16x8*)(kb + ((lch * 16) ^ swz));
      s16x8 k1 = *(const s16x8*)(kb + ((64 + lch * 16) ^ swz));
      f32x4 a = {0.f, 0.f, 0.f, 0.f};
      a = mfma16(k0, qf0, a);
      a = mfma16(k1, qf1, a);
      float pv[4];
      #pragma unroll
      for (int j = 0; j < 4; ++j) {
        int u = kt * 16 + lch * 4 + j;
        int kpos = kstart + u;
        bool win = (u >= tq) && (u < tq + 256);
        bool inr = (kpos >= 0) && (kpos < SEQ);
        float ex = __expf(a[j]);
        sum += win ? (inr ? ex : 1.0f) : 0.0f;   // pad keys: exp(0)=1 in denom
        pv[j] = (win && inr) ? ex : 0.0f;        // pad/masked: 0 in PV
      }
      pw[2 * kt]     = pk2(pv[0], pv[1]);
      pw[2 * kt + 1] = pk2(pv[2], pv[3]);
    }
    sum += __shfl_xor(sum, 16);
    sum += __shfl_xor(sum, 32);
    float inv = 1.0f / sum;   // reciprocal for query l15

    // PV output rows are query lch*4+j -> fetch that query's reciprocal.
    // sum(q) is complete in every lane with l15==q; use lanes 0..15.
    float invr[4];
    #pragma unroll
    for (int j = 0; j < 4; ++j)
      invr[j] = __shfl(inv, lch * 4 + j);

    // PV: A-frag = own-lane packed (unnormalized) P, B = Vt sigma rows
    f32x4 oa[4] = {};
    #pragma unroll
    for (int c = 0; c < 10; ++c) {
      union { unsigned int wd[4]; s16x8 v; } af;
      af.wd[0] = pw[4 * c];
      af.wd[1] = pw[4 * c + 1];
      af.wd[2] = pw[4 * c + 2];
      af.wd[3] = pw[4 * c + 3];
      #pragma unroll
      for (int nt = 0; nt < 4; ++nt) {
        const unsigned short* vp = &Vt[(nt * 16 + l15) * VSTR + c * 32 + lch * 8];
        union { unsigned long long q[2]; s16x8 v; } bf_;
        bf_.q[0] = *(const unsigned long long*)vp;
        bf_.q[1] = *(const unsigned long long*)(vp + 4);
        oa[nt] = mfma16(af.v, bf_.v, oa[nt]);
      }
    }

    // O store: normalize row (query lch*4+j) by ITS reciprocal, bounce
    // through per-wave LDS tile, then 16B/lane coalesced stores.
    unsigned short* ob = OB + w * 16 * 68;
    #pragma unroll
    for (int nt = 0; nt < 4; ++nt)
      #pragma unroll
      for (int j = 0; j < 4; ++j)
        ob[(lch * 4 + j) * 68 + nt * 16 + l15] = f2bf(oa[nt][j] * invr[j]);
    int orow = lane >> 3, ochk = lane & 7;
    #pragma unroll
    for (int half = 0; half < 2; ++half) {
      s16x8 ov = *(const s16x8*)&ob[(half * 8 + orow) * 68 + ochk * 8];
      long r = rowbase + qbase + mt * 16 + half * 8 + orow;
      *(s16x8*)(aout + r * 1024 + h * 64 + ochk * 8) = ov;
    }
  }
}

// ---------------------------------------------------------------------------
extern "C" void kernel_launch(void* const* d_in, const int* in_sizes, int n_in,
                              void* d_out, int out_size, void* d_ws, size_t ws_size,
                              hipStream_t stream) {
  const float* x  = (const float*)d_in[0];
  const float* Wq = (const float*)d_in[1];
  const float* bq = (const float*)d_in[2];
  const float* Wk = (const float*)d_in[3];
  const float* bk = (const float*)d_in[4];
  const float* Wv = (const float*)d_in[5];
  const float* bv = (const float*)d_in[6];
  const float* Wo = (const float*)d_in[7];
  const float* bo = (const float*)d_in[8];
  float* out = (float*)d_out;

  // workspace layout (bytes): total ~42.5 MB; attno aliases dead xb
  char* ws = (char*)d_ws;
  unsigned short* xb    = (unsigned short*)(ws);
  unsigned short* attno = (unsigned short*)(ws);
  unsigned short* wqkvt = (unsigned short*)(ws + 16777216);
  unsigned short* wot   = (unsigned short*)(ws + 19398656);
  unsigned short* qkv   = (unsigned short*)(ws + 21495808);

  convert_x<<<8192, 256, 0, stream>>>(x, xb, NROWS * 1024);
  transpose_qkv<<<dim3(32, 40), dim3(32, 8), 0, stream>>>(Wq, Wk, Wv, wqkvt);
  transpose_wo<<<dim3(32, 32), dim3(32, 8), 0, stream>>>(Wo, wot);

  gemm_bt<true, false><<<dim3(NROWS / 128, QKV_N / 128), 256, 0, stream>>>(
      xb, wqkvt, (void*)qkv, bq, bk, bv, NROWS, QKV_N, 1024);

  attn_win<<<dim3(64, 2, 2), 512, 0, stream>>>(qkv, attno);

  gemm_bt<false, true><<<dim3(NROWS / 128, 1024 / 128), 256, 0, stream>>>(
      attno, wot, (void*)out, bo, nullptr, nullptr, NROWS, 1024, 1024);
}